// Round 4
// baseline (177.748 us; speedup 1.0000x reference)
//
#include <hip/hip_runtime.h>

#define H 12
#define DM 768
#define HD 64
#define SEQ 2048
#define BATCH 2
#define MROWS (BATCH*SEQ)   // 4096

typedef __attribute__((ext_vector_type(8))) short short8;   // 8 bf16 (4 VGPRs)
typedef __attribute__((ext_vector_type(4))) float f32x4;
using u16 = unsigned short;
using u32 = unsigned int;

__device__ __forceinline__ float bf2f(u16 u) { return __uint_as_float(((u32)u) << 16); }
__device__ __forceinline__ u16 f2bf(float x) {
  u32 u = __float_as_uint(x);
  return (u16)((u + 0x7fffu + ((u >> 16) & 1u)) >> 16);   // RNE
}

// ------------- weight transpose + f32->bf16: dst[e*768+d] = bf16(src[d*768+e]) -------------
__global__ __launch_bounds__(256) void transpose_w4(const float* __restrict__ w0, const float* __restrict__ w1,
                                                    const float* __restrict__ w2, const float* __restrict__ w3,
                                                    u16* __restrict__ dst0)
{
  __shared__ u16 Ts[64][72];                 // +8 pad, rows 144 B (16B-aligned)
  const float* src = blockIdx.z == 0 ? w0 : blockIdx.z == 1 ? w1 : blockIdx.z == 2 ? w2 : w3;
  u16* dst = dst0 + (size_t)blockIdx.z * DM * DM;
  const int t = threadIdx.x;
  const int r0 = blockIdx.y * 64, c0 = blockIdx.x * 64;
  const int row = t >> 2, cq = (t & 3) * 16;
  const float* sp = src + (size_t)(r0 + row) * DM + c0 + cq;
  #pragma unroll
  for (int g = 0; g < 4; ++g) {
    float4 a = *reinterpret_cast<const float4*>(sp + g * 4);
    Ts[row][cq + g * 4 + 0] = f2bf(a.x);
    Ts[row][cq + g * 4 + 1] = f2bf(a.y);
    Ts[row][cq + g * 4 + 2] = f2bf(a.z);
    Ts[row][cq + g * 4 + 3] = f2bf(a.w);
  }
  __syncthreads();
  union { uint4 v[2]; u16 e[16]; } pk;
  #pragma unroll
  for (int j = 0; j < 16; ++j) pk.e[j] = Ts[cq + j][row];
  uint4* dp = reinterpret_cast<uint4*>(dst + (size_t)(c0 + row) * DM + r0 + cq);
  dp[0] = pk.v[0];
  dp[1] = pk.v[1];
}

// ---------------- GEMM: C[m][n] = A[m][:] . Bt[n][:] + bias[n] ----------------
// 128x128 tile, BK=64, 4 waves each 64x64. LDS rows are 128 B; XOR swizzle
// byte ^= (row&7)<<4 applied identically on write and read (T2, G4).
// AF32: A operand is float32 (converted to bf16 during staging); else bf16 u16.
// mode 0: dst[B,H,S,HD] bf16 (Q,K)   mode 1: dst[B,H,HD,S] bf16 (V transposed)
// mode 2: dst[M,N] float32 (final output)
template<bool AF32>
__device__ __forceinline__ void gemm_core(const void* __restrict__ Av, const u16* __restrict__ Bt,
                                          const float* __restrict__ bias, void* __restrict__ dstv,
                                          int mode, int bx, int by)
{
  __shared__ u16 As[128 * 64];
  __shared__ u16 Bs[128 * 64];
  const int t = threadIdx.x;
  const int lane = t & 63, w = t >> 6;
  const int l15 = lane & 15, l4 = lane >> 4;
  const int m0 = by * 128, n0 = bx * 128;
  const int wr = (w >> 1) * 64, wc = (w & 1) * 64;

  f32x4 acc[4][4] = {};

  for (int kt = 0; kt < DM / 64; ++kt) {
    const int k0 = kt * 64;
    #pragma unroll
    for (int c = 0; c < 4; ++c) {
      const int id = c * 256 + t;
      const int row = id >> 3, xc = id & 7;
      const int db = row * 128 + ((xc * 16) ^ ((row & 7) << 4));
      if (AF32) {
        const float* Af = reinterpret_cast<const float*>(Av) + (size_t)(m0 + row) * DM + k0 + xc * 8;
        float4 a0 = *reinterpret_cast<const float4*>(Af);
        float4 a1 = *reinterpret_cast<const float4*>(Af + 4);
        union { uint4 v; u16 e[8]; } pk;
        pk.e[0] = f2bf(a0.x); pk.e[1] = f2bf(a0.y); pk.e[2] = f2bf(a0.z); pk.e[3] = f2bf(a0.w);
        pk.e[4] = f2bf(a1.x); pk.e[5] = f2bf(a1.y); pk.e[6] = f2bf(a1.z); pk.e[7] = f2bf(a1.w);
        *reinterpret_cast<uint4*>(reinterpret_cast<char*>(As) + db) = pk.v;
      } else {
        const u16* Au = reinterpret_cast<const u16*>(Av);
        uint4 va = *reinterpret_cast<const uint4*>(Au + (size_t)(m0 + row) * DM + k0 + xc * 8);
        *reinterpret_cast<uint4*>(reinterpret_cast<char*>(As) + db) = va;
      }
      uint4 vb = *reinterpret_cast<const uint4*>(Bt + (size_t)(n0 + row) * DM + k0 + xc * 8);
      *reinterpret_cast<uint4*>(reinterpret_cast<char*>(Bs) + db) = vb;
    }
    __syncthreads();
    #pragma unroll
    for (int ks = 0; ks < 2; ++ks) {
      short8 ag[4], bg[4];
      #pragma unroll
      for (int i = 0; i < 4; ++i) {
        const int ar = wr + i * 16 + l15;
        ag[i] = *reinterpret_cast<const short8*>(reinterpret_cast<const char*>(As) +
                 ar * 128 + ((ks * 64 + l4 * 16) ^ ((ar & 7) << 4)));
        const int br = wc + i * 16 + l15;
        bg[i] = *reinterpret_cast<const short8*>(reinterpret_cast<const char*>(Bs) +
                 br * 128 + ((ks * 64 + l4 * 16) ^ ((br & 7) << 4)));
      }
      #pragma unroll
      for (int i = 0; i < 4; ++i)
        #pragma unroll
        for (int j = 0; j < 4; ++j)
          acc[i][j] = __builtin_amdgcn_mfma_f32_16x16x32_bf16(ag[i], bg[j], acc[i][j], 0, 0, 0);
    }
    __syncthreads();
  }

  // epilogue: C row = (lane>>4)*4 + reg, col = lane&15 (m89-verified layout)
  #pragma unroll
  for (int j = 0; j < 4; ++j) {
    const int gcol = n0 + wc + j * 16 + l15;
    const float bb = bias[gcol];
    #pragma unroll
    for (int i = 0; i < 4; ++i) {
      const int grow = m0 + wr + i * 16 + l4 * 4;
      if (mode == 2) {               // float32 output [M, DM]
        float* dst = reinterpret_cast<float*>(dstv);
        #pragma unroll
        for (int r = 0; r < 4; ++r)
          dst[(size_t)(grow + r) * DM + gcol] = acc[i][j][r] + bb;
      } else {
        u16* dst = reinterpret_cast<u16*>(dstv);
        const int b = grow >> 11, s = grow & (SEQ - 1);
        const int h = gcol >> 6, d = gcol & 63;
        if (mode == 0) {
          #pragma unroll
          for (int r = 0; r < 4; ++r)
            dst[((size_t)(b * H + h) * SEQ + s + r) * HD + d] = f2bf(acc[i][j][r] + bb);
        } else {  // mode 1: V transposed — 4 consecutive s → one 8B store
          union { uint2 v; u16 e[4]; } pk;
          #pragma unroll
          for (int r = 0; r < 4; ++r) pk.e[r] = f2bf(acc[i][j][r] + bb);
          *reinterpret_cast<uint2*>(dst + ((size_t)(b * H + h) * HD + d) * SEQ + s) = pk.v;
        }
      }
    }
  }
}

__global__ __launch_bounds__(256) void gemm_qkv_kernel(
    const float* __restrict__ xq, const float* __restrict__ xk, const float* __restrict__ xv,
    const u16* __restrict__ wT, const float* __restrict__ bq, const float* __restrict__ bk,
    const float* __restrict__ bv, u16* __restrict__ Qb, u16* __restrict__ Kb, u16* __restrict__ Vtb)
{
  const int z = blockIdx.z;
  const float* A    = z == 0 ? xq : z == 1 ? xk : xv;
  const u16* Bt     = wT + (size_t)z * DM * DM;
  const float* bias = z == 0 ? bq : z == 1 ? bk : bv;
  u16* dst          = z == 0 ? Qb : z == 1 ? Kb : Vtb;
  gemm_core<true>(A, Bt, bias, dst, z == 2 ? 1 : 0, blockIdx.x, blockIdx.y);
}

__global__ __launch_bounds__(256) void gemm_o_kernel(const u16* __restrict__ A, const u16* __restrict__ woT,
                                                     const float* __restrict__ bo, float* __restrict__ out)
{
  gemm_core<false>(A, woT, bo, out, 2, blockIdx.x, blockIdx.y);
}

// ---------------- flash attention ----------------
// block = 4 waves; blockIdx.x = q-tile (S/64), blockIdx.y = b*H+h.
// Wave w owns q-rows [w*16, w*16+16). K tile [t][d] natural, V tile [d][t] (pre-transposed).
__global__ __launch_bounds__(256) void attn_kernel(const u16* __restrict__ Q, const u16* __restrict__ K,
                                                   const u16* __restrict__ Vt, u16* __restrict__ attn)
{
  __shared__ u16 Qs[64 * 64], Ks[64 * 64], Vs[64 * 64];
  __shared__ u16 Ps[4][16 * 64];
  const int t = threadIdx.x;
  const int lane = t & 63, w = t >> 6;
  const int l15 = lane & 15, l4 = lane >> 4;
  const int q0 = blockIdx.x * 64;
  const int bh = blockIdx.y;
  const size_t qbase  = ((size_t)bh * SEQ + q0) * HD;
  const size_t kbase0 = (size_t)bh * SEQ * HD;
  const size_t vtbase = (size_t)bh * HD * SEQ;
  const float scale = 0.125f;   // 1/sqrt(64)

  // stage Q tile (swizzled rows of 128 B)
  #pragma unroll
  for (int c = 0; c < 2; ++c) {
    const int id = c * 256 + t;
    const int row = id >> 3, xc = id & 7;
    uint4 v = *reinterpret_cast<const uint4*>(Q + qbase + (size_t)row * HD + xc * 8);
    *reinterpret_cast<uint4*>(reinterpret_cast<char*>(Qs) + row * 128 + ((xc * 16) ^ ((row & 7) << 4))) = v;
  }
  __syncthreads();
  short8 qf[2];
  {
    const int qr = w * 16 + l15;
    #pragma unroll
    for (int ks = 0; ks < 2; ++ks)
      qf[ks] = *reinterpret_cast<const short8*>(reinterpret_cast<const char*>(Qs) +
               qr * 128 + ((ks * 64 + l4 * 16) ^ ((qr & 7) << 4)));
  }

  float m_r[4], l_r[4];
  f32x4 oacc[4] = {};
  #pragma unroll
  for (int r = 0; r < 4; ++r) { m_r[r] = -1e30f; l_r[r] = 0.f; }

  for (int kt = 0; kt < SEQ / 64; ++kt) {
    __syncthreads();   // previous iteration's K/V reads complete
    #pragma unroll
    for (int c = 0; c < 2; ++c) {
      const int id = c * 256 + t;
      const int row = id >> 3, xc = id & 7;
      const int db = row * 128 + ((xc * 16) ^ ((row & 7) << 4));
      uint4 vk = *reinterpret_cast<const uint4*>(K + kbase0 + (size_t)(kt * 64 + row) * HD + xc * 8);
      *reinterpret_cast<uint4*>(reinterpret_cast<char*>(Ks) + db) = vk;
      uint4 vv = *reinterpret_cast<const uint4*>(Vt + vtbase + (size_t)row * SEQ + kt * 64 + xc * 8);
      *reinterpret_cast<uint4*>(reinterpret_cast<char*>(Vs) + db) = vv;
    }
    __syncthreads();

    // scores: S[q][t], q = w*16 + l4*4 + r, t = cb*16 + l15
    f32x4 sacc[4] = {};
    #pragma unroll
    for (int ks = 0; ks < 2; ++ks) {
      #pragma unroll
      for (int cb = 0; cb < 4; ++cb) {
        const int krow = cb * 16 + l15;
        short8 kf = *reinterpret_cast<const short8*>(reinterpret_cast<const char*>(Ks) +
                    krow * 128 + ((ks * 64 + l4 * 16) ^ ((krow & 7) << 4)));
        sacc[cb] = __builtin_amdgcn_mfma_f32_16x16x32_bf16(qf[ks], kf, sacc[cb], 0, 0, 0);
      }
    }

    // online softmax (16-lane groups share the quarter's 4 rows)
    float pm[4], fr[4];
    #pragma unroll
    for (int r = 0; r < 4; ++r) {
      float mx = fmaxf(fmaxf(sacc[0][r], sacc[1][r]), fmaxf(sacc[2][r], sacc[3][r]));
      #pragma unroll
      for (int mask = 1; mask < 16; mask <<= 1) mx = fmaxf(mx, __shfl_xor(mx, mask));
      mx *= scale;
      const float mn = fmaxf(m_r[r], mx);
      fr[r] = __expf(m_r[r] - mn);
      m_r[r] = mn;
      pm[r] = mn;
    }
    float p[4][4];
    #pragma unroll
    for (int cb = 0; cb < 4; ++cb)
      #pragma unroll
      for (int r = 0; r < 4; ++r)
        p[cb][r] = __expf(sacc[cb][r] * scale - pm[r]);
    #pragma unroll
    for (int r = 0; r < 4; ++r) {
      float s = p[0][r] + p[1][r] + p[2][r] + p[3][r];
      #pragma unroll
      for (int mask = 1; mask < 16; mask <<= 1) s += __shfl_xor(s, mask);
      l_r[r] = l_r[r] * fr[r] + s;
      #pragma unroll
      for (int nb = 0; nb < 4; ++nb) oacc[nb][r] *= fr[r];
    }

    // P -> per-wave LDS (swizzled), then PV
    u16* Pw = Ps[w];
    #pragma unroll
    for (int cb = 0; cb < 4; ++cb)
      #pragma unroll
      for (int r = 0; r < 4; ++r) {
        const int row = l4 * 4 + r, col = cb * 16 + l15;
        *reinterpret_cast<u16*>(reinterpret_cast<char*>(Pw) +
            (row * 128 + ((col * 2) ^ ((row & 7) << 4)))) = f2bf(p[cb][r]);
      }
    __syncthreads();   // safe cross-lane visibility of P

    #pragma unroll
    for (int ks = 0; ks < 2; ++ks) {
      const int prow = l15;
      short8 pf = *reinterpret_cast<const short8*>(reinterpret_cast<const char*>(Pw) +
                  prow * 128 + ((ks * 64 + l4 * 16) ^ ((prow & 7) << 4)));
      #pragma unroll
      for (int nb = 0; nb < 4; ++nb) {
        const int vrow = nb * 16 + l15;
        short8 vf = *reinterpret_cast<const short8*>(reinterpret_cast<const char*>(Vs) +
                    vrow * 128 + ((ks * 64 + l4 * 16) ^ ((vrow & 7) << 4)));
        oacc[nb] = __builtin_amdgcn_mfma_f32_16x16x32_bf16(pf, vf, oacc[nb], 0, 0, 0);
      }
    }
  }

  // normalize + store merged-head layout [B,S,H*HD]
  const int b = bh / H, h = bh % H;
  #pragma unroll
  for (int r = 0; r < 4; ++r) {
    const float inv = 1.f / l_r[r];
    const int srow = q0 + w * 16 + l4 * 4 + r;
    const size_t base = ((size_t)(b * SEQ + srow)) * DM + h * HD;
    #pragma unroll
    for (int nb = 0; nb < 4; ++nb)
      attn[base + nb * 16 + l15] = f2bf(oacc[nb][r] * inv);
  }
}

extern "C" void kernel_launch(void* const* d_in, const int* in_sizes, int n_in,
                              void* d_out, int out_size, void* d_ws, size_t ws_size,
                              hipStream_t stream)
{
  const float* q  = (const float*)d_in[0];
  const float* k  = (const float*)d_in[1];
  const float* v  = (const float*)d_in[2];
  const float* wq = (const float*)d_in[3];
  const float* bq = (const float*)d_in[4];
  const float* wk = (const float*)d_in[5];
  const float* bk = (const float*)d_in[6];
  const float* wv = (const float*)d_in[7];
  const float* bv = (const float*)d_in[8];
  const float* wo = (const float*)d_in[9];
  const float* bo = (const float*)d_in[10];

  u16* ws = (u16*)d_ws;
  const size_t WSZ = (size_t)DM * DM;       // 589,824
  const size_t TSZ = (size_t)MROWS * DM;    // 3,145,728
  u16* wT  = ws;                 // wqT, wkT, wvT, woT (4 x WSZ)
  u16* Qb  = ws + 4 * WSZ;       // [B,H,S,HD]
  u16* Kb  = Qb + TSZ;           // [B,H,S,HD]
  u16* Vtb = Kb + TSZ;           // [B,H,HD,S]
  u16* Ab  = Vtb + TSZ;          // [M, DM] attention output (merged heads)
  // total ws use: (4*WSZ + 4*TSZ)*2 B ≈ 29.9 MB

  transpose_w4<<<dim3(12, 12, 4), 256, 0, stream>>>(wq, wk, wv, wo, wT);
  gemm_qkv_kernel<<<dim3(6, 32, 3), 256, 0, stream>>>(q, k, v, wT, bq, bk, bv, Qb, Kb, Vtb);
  attn_kernel<<<dim3(SEQ / 64, BATCH * H), 256, 0, stream>>>(Qb, Kb, Vtb, Ab);
  gemm_o_kernel<<<dim3(6, 32), 256, 0, stream>>>(Ab, wT + 3 * WSZ, bo, (float*)d_out);
}

// Round 5
// 150.217 us; speedup vs baseline: 1.1833x; 1.1833x over previous
//
#include <hip/hip_runtime.h>

#define H 12
#define DM 768
#define HD 64
#define SEQ 2048
#define BATCH 2
#define MROWS (BATCH*SEQ)   // 4096

typedef __attribute__((ext_vector_type(8))) short short8;   // 8 bf16 (4 VGPRs)
typedef __attribute__((ext_vector_type(4))) float f32x4;
using u16 = unsigned short;
using u32 = unsigned int;

__device__ __forceinline__ float bf2f(u16 u) { return __uint_as_float(((u32)u) << 16); }
__device__ __forceinline__ u16 f2bf(float x) {
  u32 u = __float_as_uint(x);
  return (u16)((u + 0x7fffu + ((u >> 16) & 1u)) >> 16);   // RNE
}
// packed f32x2 -> bf16x2 (RNE), single instruction (T12 recipe: no builtin on gfx950)
__device__ __forceinline__ u32 cvt_pk_bf16(float lo, float hi) {
  u32 r;
  asm("v_cvt_pk_bf16_f32 %0, %1, %2" : "=v"(r) : "v"(lo), "v"(hi));
  return r;
}

// ------------- weight transpose + f32->bf16: dst[e*768+d] = bf16(src[d*768+e]) -------------
__global__ __launch_bounds__(256) void transpose_w4(const float* __restrict__ w0, const float* __restrict__ w1,
                                                    const float* __restrict__ w2, const float* __restrict__ w3,
                                                    u16* __restrict__ dst0)
{
  __shared__ u16 Ts[64][72];                 // +8 pad, rows 144 B (16B-aligned)
  const float* src = blockIdx.z == 0 ? w0 : blockIdx.z == 1 ? w1 : blockIdx.z == 2 ? w2 : w3;
  u16* dst = dst0 + (size_t)blockIdx.z * DM * DM;
  const int t = threadIdx.x;
  const int r0 = blockIdx.y * 64, c0 = blockIdx.x * 64;
  const int row = t >> 2, cq = (t & 3) * 16;
  const float* sp = src + (size_t)(r0 + row) * DM + c0 + cq;
  #pragma unroll
  for (int g = 0; g < 4; ++g) {
    float4 a = *reinterpret_cast<const float4*>(sp + g * 4);
    Ts[row][cq + g * 4 + 0] = f2bf(a.x);
    Ts[row][cq + g * 4 + 1] = f2bf(a.y);
    Ts[row][cq + g * 4 + 2] = f2bf(a.z);
    Ts[row][cq + g * 4 + 3] = f2bf(a.w);
  }
  __syncthreads();
  union { uint4 v[2]; u16 e[16]; } pk;
  #pragma unroll
  for (int j = 0; j < 16; ++j) pk.e[j] = Ts[cq + j][row];
  uint4* dp = reinterpret_cast<uint4*>(dst + (size_t)(c0 + row) * DM + r0 + cq);
  dp[0] = pk.v[0];
  dp[1] = pk.v[1];
}

// ---------------- GEMM: C[m][n] = A[m][:] . Bt[n][:] + bias[n] ----------------
// 128x128 tile, BK=64, 4 waves each 64x64. LDS rows are 128 B; XOR swizzle
// byte ^= (row&7)<<4 applied identically on write and read (T2, G4).
// AF32: A operand is float32 (converted to bf16 during staging); else bf16 u16.
// mode 0: dst[B,H,S,HD] bf16 (Q,K)   mode 1: dst[B,H,HD,S] bf16 (V transposed)
// mode 2: dst[M,N] float32 (final output)
template<bool AF32>
__device__ __forceinline__ void gemm_core(const void* __restrict__ Av, const u16* __restrict__ Bt,
                                          const float* __restrict__ bias, void* __restrict__ dstv,
                                          int mode, int bx, int by)
{
  __shared__ u16 As[128 * 64];
  __shared__ u16 Bs[128 * 64];
  const int t = threadIdx.x;
  const int lane = t & 63, w = t >> 6;
  const int l15 = lane & 15, l4 = lane >> 4;
  const int m0 = by * 128, n0 = bx * 128;
  const int wr = (w >> 1) * 64, wc = (w & 1) * 64;

  f32x4 acc[4][4] = {};

  for (int kt = 0; kt < DM / 64; ++kt) {
    const int k0 = kt * 64;
    #pragma unroll
    for (int c = 0; c < 4; ++c) {
      const int id = c * 256 + t;
      const int row = id >> 3, xc = id & 7;
      const int db = row * 128 + ((xc * 16) ^ ((row & 7) << 4));
      if (AF32) {
        const float* Af = reinterpret_cast<const float*>(Av) + (size_t)(m0 + row) * DM + k0 + xc * 8;
        float4 a0 = *reinterpret_cast<const float4*>(Af);
        float4 a1 = *reinterpret_cast<const float4*>(Af + 4);
        uint4 v;
        v.x = cvt_pk_bf16(a0.x, a0.y);
        v.y = cvt_pk_bf16(a0.z, a0.w);
        v.z = cvt_pk_bf16(a1.x, a1.y);
        v.w = cvt_pk_bf16(a1.z, a1.w);
        *reinterpret_cast<uint4*>(reinterpret_cast<char*>(As) + db) = v;
      } else {
        const u16* Au = reinterpret_cast<const u16*>(Av);
        uint4 va = *reinterpret_cast<const uint4*>(Au + (size_t)(m0 + row) * DM + k0 + xc * 8);
        *reinterpret_cast<uint4*>(reinterpret_cast<char*>(As) + db) = va;
      }
      uint4 vb = *reinterpret_cast<const uint4*>(Bt + (size_t)(n0 + row) * DM + k0 + xc * 8);
      *reinterpret_cast<uint4*>(reinterpret_cast<char*>(Bs) + db) = vb;
    }
    __syncthreads();
    #pragma unroll
    for (int ks = 0; ks < 2; ++ks) {
      short8 ag[4], bg[4];
      #pragma unroll
      for (int i = 0; i < 4; ++i) {
        const int ar = wr + i * 16 + l15;
        ag[i] = *reinterpret_cast<const short8*>(reinterpret_cast<const char*>(As) +
                 ar * 128 + ((ks * 64 + l4 * 16) ^ ((ar & 7) << 4)));
        const int br = wc + i * 16 + l15;
        bg[i] = *reinterpret_cast<const short8*>(reinterpret_cast<const char*>(Bs) +
                 br * 128 + ((ks * 64 + l4 * 16) ^ ((br & 7) << 4)));
      }
      #pragma unroll
      for (int i = 0; i < 4; ++i)
        #pragma unroll
        for (int j = 0; j < 4; ++j)
          acc[i][j] = __builtin_amdgcn_mfma_f32_16x16x32_bf16(ag[i], bg[j], acc[i][j], 0, 0, 0);
    }
    __syncthreads();
  }

  // epilogue: C row = (lane>>4)*4 + reg, col = lane&15 (m89-verified layout)
  #pragma unroll
  for (int j = 0; j < 4; ++j) {
    const int gcol = n0 + wc + j * 16 + l15;
    const float bb = bias[gcol];
    #pragma unroll
    for (int i = 0; i < 4; ++i) {
      const int grow = m0 + wr + i * 16 + l4 * 4;
      if (mode == 2) {               // float32 output [M, DM]
        float* dst = reinterpret_cast<float*>(dstv);
        #pragma unroll
        for (int r = 0; r < 4; ++r)
          dst[(size_t)(grow + r) * DM + gcol] = acc[i][j][r] + bb;
      } else {
        u16* dst = reinterpret_cast<u16*>(dstv);
        const int b = grow >> 11, s = grow & (SEQ - 1);
        const int h = gcol >> 6, d = gcol & 63;
        if (mode == 0) {
          #pragma unroll
          for (int r = 0; r < 4; ++r)
            dst[((size_t)(b * H + h) * SEQ + s + r) * HD + d] = f2bf(acc[i][j][r] + bb);
        } else {  // mode 1: V transposed — 4 consecutive s → one 8B store
          union { uint2 v; u16 e[4]; } pk;
          #pragma unroll
          for (int r = 0; r < 4; ++r) pk.e[r] = f2bf(acc[i][j][r] + bb);
          *reinterpret_cast<uint2*>(dst + ((size_t)(b * H + h) * HD + d) * SEQ + s) = pk.v;
        }
      }
    }
  }
}

__global__ __launch_bounds__(256) void gemm_qkv_kernel(
    const float* __restrict__ xq, const float* __restrict__ xk, const float* __restrict__ xv,
    const u16* __restrict__ wT, const float* __restrict__ bq, const float* __restrict__ bk,
    const float* __restrict__ bv, u16* __restrict__ Qb, u16* __restrict__ Kb, u16* __restrict__ Vtb)
{
  const int z = blockIdx.z;
  const float* A    = z == 0 ? xq : z == 1 ? xk : xv;
  const u16* Bt     = wT + (size_t)z * DM * DM;
  const float* bias = z == 0 ? bq : z == 1 ? bk : bv;
  u16* dst          = z == 0 ? Qb : z == 1 ? Kb : Vtb;
  gemm_core<true>(A, Bt, bias, dst, z == 2 ? 1 : 0, blockIdx.x, blockIdx.y);
}

__global__ __launch_bounds__(256) void gemm_o_kernel(const u16* __restrict__ A, const u16* __restrict__ woT,
                                                     const float* __restrict__ bo, float* __restrict__ out)
{
  gemm_core<false>(A, woT, bo, out, 2, blockIdx.x, blockIdx.y);
}

// ---------------- flash attention (swapped-QK^T, in-lane softmax) ----------------
// block = 4 waves; blockIdx.x = q-tile (S/64), blockIdx.y = b*H+h.
// Wave w owns q-rows [w*16, w*16+16). K tile [t][d] natural, V tile [d][t] (pre-transposed).
// S^T = mfma(K-frag, Q-frag): lane holds 16 scores of q-row (lane&15);
// row softmax = 15 in-lane ops + 2 shfl_xor. P packed via v_cvt_pk_bf16_f32
// into wave-private LDS (same-wave LDS ops are in-order -> no barrier).
__global__ __launch_bounds__(256) void attn_kernel(const u16* __restrict__ Q, const u16* __restrict__ K,
                                                   const u16* __restrict__ Vt, u16* __restrict__ attn)
{
  __shared__ u16 Qs[64 * 64], Ks[64 * 64], Vs[64 * 64];
  __shared__ u16 Ps[4][16 * 64];
  const int t = threadIdx.x;
  const int lane = t & 63, w = t >> 6;
  const int l15 = lane & 15, l4 = lane >> 4;
  const int q0 = blockIdx.x * 64;
  const int bh = blockIdx.y;
  const size_t qbase  = ((size_t)bh * SEQ + q0) * HD;
  const size_t kbase0 = (size_t)bh * SEQ * HD;
  const size_t vtbase = (size_t)bh * HD * SEQ;
  const float c = 0.18033688011112042f;   // (1/sqrt(64)) * log2(e)

  // stage Q tile (swizzled rows of 128 B)
  #pragma unroll
  for (int cc = 0; cc < 2; ++cc) {
    const int id = cc * 256 + t;
    const int row = id >> 3, xc = id & 7;
    uint4 v = *reinterpret_cast<const uint4*>(Q + qbase + (size_t)row * HD + xc * 8);
    *reinterpret_cast<uint4*>(reinterpret_cast<char*>(Qs) + row * 128 + ((xc * 16) ^ ((row & 7) << 4))) = v;
  }
  __syncthreads();
  short8 qf[2];
  {
    const int qr = w * 16 + l15;
    #pragma unroll
    for (int ks = 0; ks < 2; ++ks)
      qf[ks] = *reinterpret_cast<const short8*>(reinterpret_cast<const char*>(Qs) +
               qr * 128 + ((ks * 64 + l4 * 16) ^ ((qr & 7) << 4)));
  }

  // per-lane softmax state for q-row (wave-local) = l15, raw-score domain
  float m_s = -3e38f, l_s = 0.f;
  f32x4 oacc[4] = {};

  char* Pw = reinterpret_cast<char*>(Ps[w]);
  const int pswz = (l15 & 7) << 4;

  for (int kt = 0; kt < SEQ / 64; ++kt) {
    __syncthreads();   // previous iteration's K/V reads complete
    #pragma unroll
    for (int cc = 0; cc < 2; ++cc) {
      const int id = cc * 256 + t;
      const int row = id >> 3, xc = id & 7;
      const int db = row * 128 + ((xc * 16) ^ ((row & 7) << 4));
      uint4 vk = *reinterpret_cast<const uint4*>(K + kbase0 + (size_t)(kt * 64 + row) * HD + xc * 8);
      *reinterpret_cast<uint4*>(reinterpret_cast<char*>(Ks) + db) = vk;
      uint4 vv = *reinterpret_cast<const uint4*>(Vt + vtbase + (size_t)row * SEQ + kt * 64 + xc * 8);
      *reinterpret_cast<uint4*>(reinterpret_cast<char*>(Vs) + db) = vv;
    }
    __syncthreads();

    // S^T: sacc[kb] holds S[k = kb*16 + l4*4 + r][q = l15] (swapped operands)
    f32x4 sacc[4] = {};
    #pragma unroll
    for (int ks = 0; ks < 2; ++ks) {
      #pragma unroll
      for (int kb = 0; kb < 4; ++kb) {
        const int krow = kb * 16 + l15;
        short8 kf = *reinterpret_cast<const short8*>(reinterpret_cast<const char*>(Ks) +
                    krow * 128 + ((ks * 64 + l4 * 16) ^ ((krow & 7) << 4)));
        sacc[kb] = __builtin_amdgcn_mfma_f32_16x16x32_bf16(kf, qf[ks], sacc[kb], 0, 0, 0);
      }
    }

    // in-lane row max over the 16 held scores, then 2-step cross-group reduce
    float mx = sacc[0][0];
    #pragma unroll
    for (int kb = 0; kb < 4; ++kb)
      #pragma unroll
      for (int r = 0; r < 4; ++r) mx = fmaxf(mx, sacc[kb][r]);
    mx = fmaxf(mx, __shfl_xor(mx, 16));
    mx = fmaxf(mx, __shfl_xor(mx, 32));
    const float mn = fmaxf(m_s, mx);
    const float fr = exp2f((m_s - mn) * c);
    m_s = mn;

    // exp + pack + write P (wave-private, no barrier needed), accumulate sum
    float psum = 0.f;
    #pragma unroll
    for (int kb = 0; kb < 4; ++kb) {
      #pragma unroll
      for (int pr = 0; pr < 2; ++pr) {
        const float p0 = exp2f((sacc[kb][2 * pr]     - mn) * c);
        const float p1 = exp2f((sacc[kb][2 * pr + 1] - mn) * c);
        psum += p0 + p1;
        const u32 pk = cvt_pk_bf16(p0, p1);
        // P[q = l15][t = kb*16 + l4*4 + 2*pr], byte = q*128 + col*2, swizzled
        *reinterpret_cast<u32*>(Pw + (l15 * 128 + ((kb * 32 + l4 * 8 + pr * 4) ^ pswz))) = pk;
      }
    }
    psum += __shfl_xor(psum, 16);
    psum += __shfl_xor(psum, 32);
    l_s = l_s * fr + psum;

    // gather rescale factors for this lane's PV output rows q = l4*4 + r
    float frv[4];
    #pragma unroll
    for (int r = 0; r < 4; ++r)
      frv[r] = __shfl(fr, (lane & 48) | (l4 * 4 + r));
    #pragma unroll
    for (int nb = 0; nb < 4; ++nb)
      #pragma unroll
      for (int r = 0; r < 4; ++r) oacc[nb][r] *= frv[r];

    // PV: O[q][d] += P[q][t] V[t][d]; A = P (rows q), B = V^T (rows d)
    #pragma unroll
    for (int ks = 0; ks < 2; ++ks) {
      short8 pf = *reinterpret_cast<const short8*>(Pw +
                  (l15 * 128 + ((ks * 64 + l4 * 16) ^ pswz)));
      #pragma unroll
      for (int nb = 0; nb < 4; ++nb) {
        const int vrow = nb * 16 + l15;
        short8 vf = *reinterpret_cast<const short8*>(reinterpret_cast<const char*>(Vs) +
                    vrow * 128 + ((ks * 64 + l4 * 16) ^ ((vrow & 7) << 4)));
        oacc[nb] = __builtin_amdgcn_mfma_f32_16x16x32_bf16(pf, vf, oacc[nb], 0, 0, 0);
      }
    }
  }

  // normalize + store merged-head layout [B,S,H*HD]
  float lv[4];
  #pragma unroll
  for (int r = 0; r < 4; ++r)
    lv[r] = __shfl(l_s, (lane & 48) | (l4 * 4 + r));
  const int b = bh / H, h = bh % H;
  #pragma unroll
  for (int r = 0; r < 4; ++r) {
    const float inv = 1.f / lv[r];
    const int srow = q0 + w * 16 + l4 * 4 + r;
    const size_t base = ((size_t)(b * SEQ + srow)) * DM + h * HD;
    #pragma unroll
    for (int nb = 0; nb < 4; ++nb)
      attn[base + nb * 16 + l15] = f2bf(oacc[nb][r] * inv);
  }
}

extern "C" void kernel_launch(void* const* d_in, const int* in_sizes, int n_in,
                              void* d_out, int out_size, void* d_ws, size_t ws_size,
                              hipStream_t stream)
{
  const float* q  = (const float*)d_in[0];
  const float* k  = (const float*)d_in[1];
  const float* v  = (const float*)d_in[2];
  const float* wq = (const float*)d_in[3];
  const float* bq = (const float*)d_in[4];
  const float* wk = (const float*)d_in[5];
  const float* bk = (const float*)d_in[6];
  const float* wv = (const float*)d_in[7];
  const float* bv = (const float*)d_in[8];
  const float* wo = (const float*)d_in[9];
  const float* bo = (const float*)d_in[10];

  u16* ws = (u16*)d_ws;
  const size_t WSZ = (size_t)DM * DM;       // 589,824
  const size_t TSZ = (size_t)MROWS * DM;    // 3,145,728
  u16* wT  = ws;                 // wqT, wkT, wvT, woT (4 x WSZ)
  u16* Qb  = ws + 4 * WSZ;       // [B,H,S,HD]
  u16* Kb  = Qb + TSZ;           // [B,H,S,HD]
  u16* Vtb = Kb + TSZ;           // [B,H,HD,S]
  u16* Ab  = Vtb + TSZ;          // [M, DM] attention output (merged heads)

  transpose_w4<<<dim3(12, 12, 4), 256, 0, stream>>>(wq, wk, wv, wo, wT);
  gemm_qkv_kernel<<<dim3(6, 32, 3), 256, 0, stream>>>(q, k, v, wT, bq, bk, bv, Qb, Kb, Vtb);
  attn_kernel<<<dim3(SEQ / 64, BATCH * H), 256, 0, stream>>>(Qb, Kb, Vtb, Ab);
  gemm_o_kernel<<<dim3(6, 32), 256, 0, stream>>>(Ab, wT + 3 * WSZ, bo, (float*)d_out);
}

// Round 6
// 145.176 us; speedup vs baseline: 1.2244x; 1.0347x over previous
//
#include <hip/hip_runtime.h>

#define H 12
#define DM 768
#define HD 64
#define SEQ 2048
#define BATCH 2
#define MROWS (BATCH*SEQ)   // 4096

typedef __attribute__((ext_vector_type(8))) short short8;   // 8 bf16 (4 VGPRs)
typedef __attribute__((ext_vector_type(4))) float f32x4;
using u16 = unsigned short;
using u32 = unsigned int;

__device__ __forceinline__ float bf2f(u16 u) { return __uint_as_float(((u32)u) << 16); }
__device__ __forceinline__ u16 f2bf(float x) {
  u32 u = __float_as_uint(x);
  return (u16)((u + 0x7fffu + ((u >> 16) & 1u)) >> 16);   // RNE
}
// packed f32x2 -> bf16x2 (RNE), single instruction (T12 recipe: no builtin on gfx950)
__device__ __forceinline__ u32 cvt_pk_bf16(float lo, float hi) {
  u32 r;
  asm("v_cvt_pk_bf16_f32 %0, %1, %2" : "=v"(r) : "v"(lo), "v"(hi));
  return r;
}
// async global->LDS, 16B per lane; LDS dest = wave-uniform base + lane*16 (m97/m104)
__device__ __forceinline__ void gl2lds16(const u16* __restrict__ g, u16* l) {
  __builtin_amdgcn_global_load_lds(
      (const __attribute__((address_space(1))) unsigned int*)g,
      (__attribute__((address_space(3))) unsigned int*)l,
      16, 0, 0);
}

// ------------- weight transpose + f32->bf16: dst[e*768+d] = bf16(src[d*768+e]) -------------
__global__ __launch_bounds__(256) void transpose_w4(const float* __restrict__ w0, const float* __restrict__ w1,
                                                    const float* __restrict__ w2, const float* __restrict__ w3,
                                                    u16* __restrict__ dst0)
{
  __shared__ u16 Ts[64][72];                 // +8 pad, rows 144 B (16B-aligned)
  const float* src = blockIdx.z == 0 ? w0 : blockIdx.z == 1 ? w1 : blockIdx.z == 2 ? w2 : w3;
  u16* dst = dst0 + (size_t)blockIdx.z * DM * DM;
  const int t = threadIdx.x;
  const int r0 = blockIdx.y * 64, c0 = blockIdx.x * 64;
  const int row = t >> 2, cq = (t & 3) * 16;
  const float* sp = src + (size_t)(r0 + row) * DM + c0 + cq;
  #pragma unroll
  for (int g = 0; g < 4; ++g) {
    float4 a = *reinterpret_cast<const float4*>(sp + g * 4);
    Ts[row][cq + g * 4 + 0] = f2bf(a.x);
    Ts[row][cq + g * 4 + 1] = f2bf(a.y);
    Ts[row][cq + g * 4 + 2] = f2bf(a.z);
    Ts[row][cq + g * 4 + 3] = f2bf(a.w);
  }
  __syncthreads();
  union { uint4 v[2]; u16 e[16]; } pk;
  #pragma unroll
  for (int j = 0; j < 16; ++j) pk.e[j] = Ts[cq + j][row];
  uint4* dp = reinterpret_cast<uint4*>(dst + (size_t)(c0 + row) * DM + r0 + cq);
  dp[0] = pk.v[0];
  dp[1] = pk.v[1];
}

// ---------------- GEMM: C[m][n] = A[m][:] . Bt[n][:] + bias[n] ----------------
// 128x128 tile, BK=64, 4 waves each 64x64. LDS rows are 128 B; XOR swizzle
// byte ^= (row&7)<<4 applied identically on write and read (T2, G4).
template<bool AF32>
__device__ __forceinline__ void gemm_core(const void* __restrict__ Av, const u16* __restrict__ Bt,
                                          const float* __restrict__ bias, void* __restrict__ dstv,
                                          int mode, int bx, int by)
{
  __shared__ u16 As[128 * 64];
  __shared__ u16 Bs[128 * 64];
  const int t = threadIdx.x;
  const int lane = t & 63, w = t >> 6;
  const int l15 = lane & 15, l4 = lane >> 4;
  const int m0 = by * 128, n0 = bx * 128;
  const int wr = (w >> 1) * 64, wc = (w & 1) * 64;

  f32x4 acc[4][4] = {};

  for (int kt = 0; kt < DM / 64; ++kt) {
    const int k0 = kt * 64;
    #pragma unroll
    for (int c = 0; c < 4; ++c) {
      const int id = c * 256 + t;
      const int row = id >> 3, xc = id & 7;
      const int db = row * 128 + ((xc * 16) ^ ((row & 7) << 4));
      if (AF32) {
        const float* Af = reinterpret_cast<const float*>(Av) + (size_t)(m0 + row) * DM + k0 + xc * 8;
        float4 a0 = *reinterpret_cast<const float4*>(Af);
        float4 a1 = *reinterpret_cast<const float4*>(Af + 4);
        uint4 v;
        v.x = cvt_pk_bf16(a0.x, a0.y);
        v.y = cvt_pk_bf16(a0.z, a0.w);
        v.z = cvt_pk_bf16(a1.x, a1.y);
        v.w = cvt_pk_bf16(a1.z, a1.w);
        *reinterpret_cast<uint4*>(reinterpret_cast<char*>(As) + db) = v;
      } else {
        const u16* Au = reinterpret_cast<const u16*>(Av);
        uint4 va = *reinterpret_cast<const uint4*>(Au + (size_t)(m0 + row) * DM + k0 + xc * 8);
        *reinterpret_cast<uint4*>(reinterpret_cast<char*>(As) + db) = va;
      }
      uint4 vb = *reinterpret_cast<const uint4*>(Bt + (size_t)(n0 + row) * DM + k0 + xc * 8);
      *reinterpret_cast<uint4*>(reinterpret_cast<char*>(Bs) + db) = vb;
    }
    __syncthreads();
    #pragma unroll
    for (int ks = 0; ks < 2; ++ks) {
      short8 ag[4], bg[4];
      #pragma unroll
      for (int i = 0; i < 4; ++i) {
        const int ar = wr + i * 16 + l15;
        ag[i] = *reinterpret_cast<const short8*>(reinterpret_cast<const char*>(As) +
                 ar * 128 + ((ks * 64 + l4 * 16) ^ ((ar & 7) << 4)));
        const int br = wc + i * 16 + l15;
        bg[i] = *reinterpret_cast<const short8*>(reinterpret_cast<const char*>(Bs) +
                 br * 128 + ((ks * 64 + l4 * 16) ^ ((br & 7) << 4)));
      }
      #pragma unroll
      for (int i = 0; i < 4; ++i)
        #pragma unroll
        for (int j = 0; j < 4; ++j)
          acc[i][j] = __builtin_amdgcn_mfma_f32_16x16x32_bf16(ag[i], bg[j], acc[i][j], 0, 0, 0);
    }
    __syncthreads();
  }

  // epilogue: C row = (lane>>4)*4 + reg, col = lane&15 (m89-verified layout)
  #pragma unroll
  for (int j = 0; j < 4; ++j) {
    const int gcol = n0 + wc + j * 16 + l15;
    const float bb = bias[gcol];
    #pragma unroll
    for (int i = 0; i < 4; ++i) {
      const int grow = m0 + wr + i * 16 + l4 * 4;
      if (mode == 2) {               // float32 output [M, DM]
        float* dst = reinterpret_cast<float*>(dstv);
        #pragma unroll
        for (int r = 0; r < 4; ++r)
          dst[(size_t)(grow + r) * DM + gcol] = acc[i][j][r] + bb;
      } else {
        u16* dst = reinterpret_cast<u16*>(dstv);
        const int b = grow >> 11, s = grow & (SEQ - 1);
        const int h = gcol >> 6, d = gcol & 63;
        if (mode == 0) {
          #pragma unroll
          for (int r = 0; r < 4; ++r)
            dst[((size_t)(b * H + h) * SEQ + s + r) * HD + d] = f2bf(acc[i][j][r] + bb);
        } else {  // mode 1: V transposed — 4 consecutive s → one 8B store
          union { uint2 v; u16 e[4]; } pk;
          #pragma unroll
          for (int r = 0; r < 4; ++r) pk.e[r] = f2bf(acc[i][j][r] + bb);
          *reinterpret_cast<uint2*>(dst + ((size_t)(b * H + h) * HD + d) * SEQ + s) = pk.v;
        }
      }
    }
  }
}

__global__ __launch_bounds__(256) void gemm_qkv_kernel(
    const float* __restrict__ xq, const float* __restrict__ xk, const float* __restrict__ xv,
    const u16* __restrict__ wT, const float* __restrict__ bq, const float* __restrict__ bk,
    const float* __restrict__ bv, u16* __restrict__ Qb, u16* __restrict__ Kb, u16* __restrict__ Vtb)
{
  const int z = blockIdx.z;
  const float* A    = z == 0 ? xq : z == 1 ? xk : xv;
  const u16* Bt     = wT + (size_t)z * DM * DM;
  const float* bias = z == 0 ? bq : z == 1 ? bk : bv;
  u16* dst          = z == 0 ? Qb : z == 1 ? Kb : Vtb;
  gemm_core<true>(A, Bt, bias, dst, z == 2 ? 1 : 0, blockIdx.x, blockIdx.y);
}

__global__ __launch_bounds__(256) void gemm_o_kernel(const u16* __restrict__ A, const u16* __restrict__ woT,
                                                     const float* __restrict__ bo, float* __restrict__ out)
{
  gemm_core<false>(A, woT, bo, out, 2, blockIdx.x, blockIdx.y);
}

// ---------------- flash attention ----------------
// Swapped-QK^T in-lane softmax (T12-lite) + global_load_lds staging with
// inverse-swizzled global source (m173) + double-buffered K/V with raw
// s_barrier + counted vmcnt (T3/T4-lite, 1 barrier/iter) + defer-max (T13).
__global__ __launch_bounds__(256) void attn_kernel(const u16* __restrict__ Q, const u16* __restrict__ K,
                                                   const u16* __restrict__ Vt, u16* __restrict__ attn)
{
  __shared__ u16 Qs[64 * 64];
  __shared__ u16 Ks[2][64 * 64];
  __shared__ u16 Vs[2][64 * 64];
  __shared__ u16 Ps[4][16 * 64];
  const int t = threadIdx.x;
  const int lane = t & 63, w = t >> 6;
  const int l15 = lane & 15, l4 = lane >> 4;
  const int q0 = blockIdx.x * 64;
  const int bh = blockIdx.y;
  const size_t qbase  = ((size_t)bh * SEQ + q0) * HD;
  const size_t kbase0 = (size_t)bh * SEQ * HD;
  const size_t vtbase = (size_t)bh * HD * SEQ;
  const float c0 = 0.18033688011112042f;   // (1/sqrt(64)) * log2(e)

  // staging geometry: lane covers 16B at linear LDS chunk ci*1024 + lane*16.
  // row = ci*8 + (lane>>3); global col pre-swizzled so LDS (linear) matches the
  // swizzled read layout: elem col = 8 * ((lane&7) ^ (lane>>3)).
  const int srow = lane >> 3;
  const int scol = ((lane & 7) ^ srow) * 8;

  // prologue: Q then K/V tile 0 (async)
  #pragma unroll
  for (int j = 0; j < 2; ++j) {
    const int ci = w * 2 + j;
    gl2lds16(Q + qbase + (size_t)(ci * 8 + srow) * HD + scol, &Qs[ci * 512]);
  }
  #pragma unroll
  for (int j = 0; j < 2; ++j) {
    const int ci = w * 2 + j;
    const int row = ci * 8 + srow;
    gl2lds16(K + kbase0 + (size_t)row * HD + scol, &Ks[0][ci * 512]);
    gl2lds16(Vt + vtbase + (size_t)row * SEQ + scol, &Vs[0][ci * 512]);
  }
  asm volatile("s_waitcnt vmcnt(4)" ::: "memory");   // my Q loads landed
  __builtin_amdgcn_s_barrier();                      // everyone's Q landed

  short8 qf[2];
  {
    const int qr = w * 16 + l15;
    #pragma unroll
    for (int ks = 0; ks < 2; ++ks)
      qf[ks] = *reinterpret_cast<const short8*>(reinterpret_cast<const char*>(Qs) +
               qr * 128 + ((ks * 64 + l4 * 16) ^ ((qr & 7) << 4)));
  }

  float m_s = -3e38f, l_s = 0.f;
  f32x4 oacc[4] = {};
  char* Pw = reinterpret_cast<char*>(Ps[w]);
  const int pswz = (l15 & 7) << 4;
  int cur = 0;

  for (int kt = 0; kt < SEQ / 64; ++kt) {
    asm volatile("s_waitcnt vmcnt(0)" ::: "memory"); // my K/V tile-kt loads landed
    __builtin_amdgcn_s_barrier();                    // everyone's landed; prev reads done

    if (kt + 1 < SEQ / 64) {                         // async prefetch next tile
      const int nxt = cur ^ 1;
      #pragma unroll
      for (int j = 0; j < 2; ++j) {
        const int ci = w * 2 + j;
        const int row = ci * 8 + srow;
        gl2lds16(K + kbase0 + (size_t)((kt + 1) * 64 + row) * HD + scol, &Ks[nxt][ci * 512]);
        gl2lds16(Vt + vtbase + (size_t)row * SEQ + (kt + 1) * 64 + scol, &Vs[nxt][ci * 512]);
      }
    }

    // S^T: sacc[kb] holds S[k = kb*16 + l4*4 + r][q = l15] (swapped operands)
    f32x4 sacc[4] = {};
    #pragma unroll
    for (int ks = 0; ks < 2; ++ks) {
      #pragma unroll
      for (int kb = 0; kb < 4; ++kb) {
        const int krow = kb * 16 + l15;
        short8 kf = *reinterpret_cast<const short8*>(reinterpret_cast<const char*>(Ks[cur]) +
                    krow * 128 + ((ks * 64 + l4 * 16) ^ ((krow & 7) << 4)));
        sacc[kb] = __builtin_amdgcn_mfma_f32_16x16x32_bf16(kf, qf[ks], sacc[kb], 0, 0, 0);
      }
    }

    // row max (in-lane over 16 scores + 2 cross-group reduces)
    float mx = sacc[0][0];
    #pragma unroll
    for (int kb = 0; kb < 4; ++kb)
      #pragma unroll
      for (int r = 0; r < 4; ++r) mx = fmaxf(mx, sacc[kb][r]);
    mx = fmaxf(mx, __shfl_xor(mx, 16));
    mx = fmaxf(mx, __shfl_xor(mx, 32));

    // T13 defer-max: only rescale when some row's max grew by > 8 (exp2 domain)
    if (__any((mx - m_s) * c0 > 8.f)) {
      const float mn = fmaxf(m_s, mx);
      const float fr = exp2f((m_s - mn) * c0);
      m_s = mn;
      l_s *= fr;
      float frv[4];
      #pragma unroll
      for (int r = 0; r < 4; ++r)
        frv[r] = __shfl(fr, (lane & 48) | (l4 * 4 + r));
      #pragma unroll
      for (int nb = 0; nb < 4; ++nb)
        #pragma unroll
        for (int r = 0; r < 4; ++r) oacc[nb][r] *= frv[r];
    }

    // exp + pack + write P (wave-private LDS, b64 writes), accumulate sum
    float psum = 0.f;
    #pragma unroll
    for (int kb = 0; kb < 4; ++kb) {
      const float p0 = exp2f((sacc[kb][0] - m_s) * c0);
      const float p1 = exp2f((sacc[kb][1] - m_s) * c0);
      const float p2 = exp2f((sacc[kb][2] - m_s) * c0);
      const float p3 = exp2f((sacc[kb][3] - m_s) * c0);
      psum += (p0 + p1) + (p2 + p3);
      uint2 pk;
      pk.x = cvt_pk_bf16(p0, p1);
      pk.y = cvt_pk_bf16(p2, p3);
      // P[q=l15][t = kb*16 + l4*4 + {0..3}], byte = q*128 + col*2, swizzled
      *reinterpret_cast<uint2*>(Pw + (l15 * 128 + ((kb * 32 + l4 * 8) ^ pswz))) = pk;
    }
    psum += __shfl_xor(psum, 16);
    psum += __shfl_xor(psum, 32);
    l_s += psum;

    // PV: O[q][d] += P[q][t] V[t][d]; A = P (rows q), B = V^T (rows d)
    #pragma unroll
    for (int ks = 0; ks < 2; ++ks) {
      short8 pf = *reinterpret_cast<const short8*>(Pw +
                  (l15 * 128 + ((ks * 64 + l4 * 16) ^ pswz)));
      #pragma unroll
      for (int nb = 0; nb < 4; ++nb) {
        const int vrow = nb * 16 + l15;
        short8 vf = *reinterpret_cast<const short8*>(reinterpret_cast<const char*>(Vs[cur]) +
                    vrow * 128 + ((ks * 64 + l4 * 16) ^ ((vrow & 7) << 4)));
        oacc[nb] = __builtin_amdgcn_mfma_f32_16x16x32_bf16(pf, vf, oacc[nb], 0, 0, 0);
      }
    }
    cur ^= 1;
  }

  // normalize + store merged-head layout [B,S,H*HD]
  float lv[4];
  #pragma unroll
  for (int r = 0; r < 4; ++r)
    lv[r] = __shfl(l_s, (lane & 48) | (l4 * 4 + r));
  const int b = bh / H, h = bh % H;
  #pragma unroll
  for (int r = 0; r < 4; ++r) {
    const float inv = 1.f / lv[r];
    const int srow2 = q0 + w * 16 + l4 * 4 + r;
    const size_t base = ((size_t)(b * SEQ + srow2)) * DM + h * HD;
    #pragma unroll
    for (int nb = 0; nb < 4; ++nb)
      attn[base + nb * 16 + l15] = f2bf(oacc[nb][r] * inv);
  }
}

extern "C" void kernel_launch(void* const* d_in, const int* in_sizes, int n_in,
                              void* d_out, int out_size, void* d_ws, size_t ws_size,
                              hipStream_t stream)
{
  const float* q  = (const float*)d_in[0];
  const float* k  = (const float*)d_in[1];
  const float* v  = (const float*)d_in[2];
  const float* wq = (const float*)d_in[3];
  const float* bq = (const float*)d_in[4];
  const float* wk = (const float*)d_in[5];
  const float* bk = (const float*)d_in[6];
  const float* wv = (const float*)d_in[7];
  const float* bv = (const float*)d_in[8];
  const float* wo = (const float*)d_in[9];
  const float* bo = (const float*)d_in[10];

  u16* ws = (u16*)d_ws;
  const size_t WSZ = (size_t)DM * DM;       // 589,824
  const size_t TSZ = (size_t)MROWS * DM;    // 3,145,728
  u16* wT  = ws;                 // wqT, wkT, wvT, woT (4 x WSZ)
  u16* Qb  = ws + 4 * WSZ;       // [B,H,S,HD]
  u16* Kb  = Qb + TSZ;           // [B,H,S,HD]
  u16* Vtb = Kb + TSZ;           // [B,H,HD,S]
  u16* Ab  = Vtb + TSZ;          // [M, DM] attention output (merged heads)

  transpose_w4<<<dim3(12, 12, 4), 256, 0, stream>>>(wq, wk, wv, wo, wT);
  gemm_qkv_kernel<<<dim3(6, 32, 3), 256, 0, stream>>>(q, k, v, wT, bq, bk, bv, Qb, Kb, Vtb);
  attn_kernel<<<dim3(SEQ / 64, BATCH * H), 256, 0, stream>>>(Qb, Kb, Vtb, Ab);
  gemm_o_kernel<<<dim3(6, 32), 256, 0, stream>>>(Ab, wT + 3 * WSZ, bo, (float*)d_out);
}